// Round 1
// 183.918 us; speedup vs baseline: 1.0104x; 1.0104x over previous
//
#include <hip/hip_runtime.h>
#include <math.h>

// Problem constants (B=4, T=2048, C=576, H=12, D=48)
#define Bn 4
#define Tn 2048
#define Cn 576
#define Hn 12
#define Dn 48
#define Mn (Bn*Tn)          // 8192 rows

// log2(e) / sqrt(48) — folded into q so attention uses exp2 directly
#define QSCALE (1.4426950408889634f * 0.14433756729740643f)

typedef short  short8  __attribute__((ext_vector_type(8)));   // 8 bf16 (4 VGPRs)
typedef float  floatx4 __attribute__((ext_vector_type(4)));   // MFMA acc
typedef unsigned short ushort_t;
typedef unsigned short ushort8_t __attribute__((ext_vector_type(8))); // 16B

static __device__ __forceinline__ unsigned short f2bf(float f) {
    union { float f; unsigned int u; } v; v.f = f;
    unsigned int r = v.u + 0x7FFFu + ((v.u >> 16) & 1u);   // round-to-nearest-even
    return (unsigned short)(r >> 16);
}

// truncation-pack two fp32 -> packed bf16x2 (P >= 0, rel err <= 2^-8)
static __device__ __forceinline__ unsigned int pack_trunc(float a, float b) {
    union { float f; unsigned int u; } ua, ub; ua.f = a; ub.f = b;
    return (ua.u >> 16) | (ub.u & 0xFFFF0000u);
}

// async global->LDS, 16B per lane; lane l's data lands at lds + l*16 (lane-linear)
static __device__ __forceinline__ void gload16(void* lds, const void* g) {
    __builtin_amdgcn_global_load_lds(
        (const __attribute__((address_space(1))) void*)g,
        (__attribute__((address_space(3))) void*)lds, 16, 0, 0);
}

// counted vmcnt + full lgkm drain (T4: never vmcnt(0) in steady state).
// if-constexpr dispatch because waitcnt immediates must be literals.
template<int N> static __device__ __forceinline__ void wait_vm_lg() {
    if constexpr (N == 0)
        asm volatile("s_waitcnt vmcnt(0) lgkmcnt(0)" ::: "memory");
    else if constexpr (N == 3)
        asm volatile("s_waitcnt vmcnt(3) lgkmcnt(0)" ::: "memory");
    else if constexpr (N == 5)
        asm volatile("s_waitcnt vmcnt(5) lgkmcnt(0)" ::: "memory");
    else if constexpr (N == 6)
        asm volatile("s_waitcnt vmcnt(6) lgkmcnt(0)" ::: "memory");
    else if constexpr (N == 10)
        asm volatile("s_waitcnt vmcnt(10) lgkmcnt(0)" ::: "memory");
    else
        static_assert(N == -12345, "unsupported waitcnt immediate");
}

// ---------------------------------------------------------------------------
// fused fp32 -> bf16 cast of all three inputs (one launch)
// ---------------------------------------------------------------------------
__global__ __launch_bounds__(256)
void cast3(const float* __restrict__ a, ushort_t* __restrict__ oa, int na4,
           const float* __restrict__ b, ushort_t* __restrict__ ob, int nb4,
           const float* __restrict__ c, ushort_t* __restrict__ oc, int nc4)
{
    int i = blockIdx.x * 256 + threadIdx.x;
    const float* src; ushort_t* dst; int idx;
    if (i < na4)                  { src = a; dst = oa; idx = i; }
    else if (i < na4 + nb4)       { src = b; dst = ob; idx = i - na4; }
    else if (i < na4 + nb4 + nc4) { src = c; dst = oc; idx = i - na4 - nb4; }
    else return;
    float4 v = ((const float4*)src)[idx];
    ushort4 o;
    o.x = f2bf(v.x); o.y = f2bf(v.y); o.z = f2bf(v.z); o.w = f2bf(v.w);
    ((ushort4*)dst)[idx] = o;
}

// ---------------------------------------------------------------------------
// MFMA bf16 GEMM: out = A[M,576] @ W[N,576]^T.
// ROUND-10 K-loop: 4-buffer / 3-ahead pipeline with COUNTED vmcnt (T3+T4).
// Previous 2-buffer loop drained vmcnt(0) at every __syncthreads -> each of
// the 18 K-steps paid full load latency (MfmaUtil 10%, nothing busy).
// Now loads for step j+3 stay in flight across ~3 iterations; barrier is raw
// s_barrier preceded by s_waitcnt vmcnt((AH-1)*PW) lgkmcnt(0):
//   - counted vmcnt: own step-(j+1) DMAs landed (all waves do same -> buffer
//     ready after barrier)
//   - lgkmcnt(0): this iteration's ds_reads drained before any wave overwrites
//     that buffer next iteration (NBUF = AH+1 makes write follow read by
//     exactly one barrier)
// Block tile MTILE(M) x 64(N), BK=32, 4 waves stacked in M.
// XCD SWIZZLE: bid = xcd + 8*slot; n = slot%NB; m-group = xcd + 8*(slot/NB).
// COALESCED EPILOGUE (MODE 0): C staged to LDS (reusing staging buffers), then
// cooperative 16B-chunk writes (q/k: 96B head-runs; v: LDS transpose -> 512B
// runs in [B,H,48,T]).  MODE 1: fp32 row-major direct (64B runs).
// ---------------------------------------------------------------------------
template<int MODE, int MTILE>
__global__ __launch_bounds__(256)
void gemm_mfma(const ushort_t* __restrict__ A, const ushort_t* __restrict__ W,
               ushort_t* __restrict__ outb, float* __restrict__ outf)
{
    constexpr int SA   = MTILE / 16;      // A segments
    constexpr int NSEG = SA + 4;          // + B segments (NTILE=64)
    constexpr int PW   = NSEG / 4;        // staging loads per wave per K-step
    constexpr int MF   = MTILE / 64;      // m-frags per wave
    constexpr int NB   = (MODE == 0) ? 27 : 9;
    constexpr int NST  = Cn / 32;         // 18 K-steps
    constexpr int AH   = 3;               // prefetch depth (steps ahead)
    constexpr int NBUF = 4;               // AH+1 ring buffers
    __shared__ __align__(16) ushort_t Ls[NBUF][NSEG][512];

    const int tid  = threadIdx.x;
    const int wave = tid >> 6;
    const int lane = tid & 63;
    const int m    = lane & 15;
    const int g    = lane >> 4;
    const int bid  = blockIdx.x;
    const int xcd  = bid & 7;
    const int slot = bid >> 3;
    const int n0   = (slot % NB) * 64;
    const int m0   = (xcd + 8 * (slot / NB)) * MTILE;

    floatx4 acc[MF][4];
    #pragma unroll
    for (int i = 0; i < MF; ++i)
        #pragma unroll
        for (int j = 0; j < 4; ++j)
            acc[i][j] = (floatx4){0.f, 0.f, 0.f, 0.f};

    const char* gp[PW];
    int         si[PW];
    #pragma unroll
    for (int i = 0; i < PW; ++i) {
        int s = wave + i * 4;
        si[i] = s;
        gp[i] = (s < SA)
            ? (const char*)(A + (size_t)(m0 + s * 16 + m) * Cn + g * 8)
            : (const char*)(W + (size_t)(n0 + (s - SA) * 16 + m) * Cn + g * 8);
    }

    // prologue: stage K-steps 0..AH-1 into bufs 0..AH-1 (all async, in order)
    #pragma unroll
    for (int s = 0; s < AH; ++s)
        #pragma unroll
        for (int i = 0; i < PW; ++i) { gload16(&Ls[s][si[i]][0], gp[i]); gp[i] += 64; }
    wait_vm_lg<(AH - 1) * PW>();          // own step-0 DMAs landed
    __builtin_amdgcn_s_barrier();         // everyone's step-0 landed

    for (int j = 0; j < NST; ++j) {
        if (j + AH < NST) {   // issue step j+AH into ring slot (stays in flight)
            #pragma unroll
            for (int i = 0; i < PW; ++i) {
                gload16(&Ls[(j + AH) & (NBUF - 1)][si[i]][0], gp[i]);
                gp[i] += 64;
            }
        }
        const int buf = j & (NBUF - 1);
        short8 bf4[4];
        #pragma unroll
        for (int jj = 0; jj < 4; ++jj)
            bf4[jj] = *(const short8*)&Ls[buf][SA + jj][lane * 8];
        #pragma unroll
        for (int i = 0; i < MF; ++i) {
            short8 af = *(const short8*)&Ls[buf][wave * MF + i][lane * 8];
            #pragma unroll
            for (int jj = 0; jj < 4; ++jj)
                acc[i][jj] = __builtin_amdgcn_mfma_f32_16x16x32_bf16(af, bf4[jj], acc[i][jj], 0, 0, 0);
        }
        // steady state: allow steps j+2..j+AH to remain in flight; tail: step down
        if (j < NST - AH)        wait_vm_lg<(AH - 1) * PW>();
        else if (j == NST - AH)  wait_vm_lg<(AH - 2) * PW>();
        else                     wait_vm_lg<0>();
        __builtin_amdgcn_s_barrier();
    }

    // ---- epilogue: C/D layout col = lane&15 (n), row = (lane>>4)*4 + reg ----
    const size_t per = (size_t)Bn * Hn * Tn * Dn;
    if (MODE == 0) {
        const int which = n0 / Cn;
        const int nb    = n0 - which * Cn;
        const int b     = m0 >> 11;          // MTILE | 2048 -> no straddle
        const int t0g   = m0 & 2047;
        ushort_t* Lc = (ushort_t*)&Ls[0][0][0];   // reuse staging LDS (40KB)
        if (which == 2) {
            // stage transposed: Lv[col(64)][row(MTILE)+8 pad]
            constexpr int RS = MTILE + 8;
            #pragma unroll
            for (int i = 0; i < MF; ++i)
                #pragma unroll
                for (int j = 0; j < 4; ++j) {
                    ushort4 pk;
                    pk.x = f2bf(acc[i][j][0]); pk.y = f2bf(acc[i][j][1]);
                    pk.z = f2bf(acc[i][j][2]); pk.w = f2bf(acc[i][j][3]);
                    *(ushort4*)&Lc[(j * 16 + m) * RS + wave * (MTILE / 4) + i * 16 + g * 4] = pk;
                }
            __syncthreads();
            // write [B,H,48,T]: 16B chunks, consecutive threads -> consecutive t
            constexpr int CPC = MTILE / 8;            // chunks per col
            constexpr int NIT = 64 * CPC / 256;       // write iterations
            #pragma unroll
            for (int it = 0; it < NIT; ++it) {
                int c    = tid + it * 256;
                int col  = c / CPC;
                int rowc = (c - col * CPC) * 8;
                int n    = nb + col;
                int h    = n / 48;
                int d    = n - h * 48;
                ushort_t* dst = outb + 2 * per
                    + (((size_t)(b * Hn + h) * Dn + d) * Tn) + t0g + rowc;
                *(ushort8_t*)dst = *(const ushort8_t*)&Lc[col * RS + rowc];
            }
        } else {
            const float sc = (which == 0) ? QSCALE : 1.0f;
            // stage row-major: Lr[row(MTILE)][col(64)+16 pad] (exactly 40KB at 256)
            #pragma unroll
            for (int i = 0; i < MF; ++i)
                #pragma unroll
                for (int j = 0; j < 4; ++j)
                    #pragma unroll
                    for (int r = 0; r < 4; ++r)
                        Lc[(wave * (MTILE / 4) + i * 16 + g * 4 + r) * 80 + j * 16 + m] =
                            f2bf(acc[i][j][r] * sc);
            __syncthreads();
            // write [B,H,T,48]: 16B chunks never straddle a head (8 | 48)
            constexpr int NIT = MTILE * 8 / 256;
            #pragma unroll
            for (int it = 0; it < NIT; ++it) {
                int c   = tid + it * 256;
                int row = c >> 3;
                int c8  = (c & 7) * 8;
                int n   = nb + c8;
                int h   = n / 48;
                int d   = n - h * 48;
                ushort_t* dst = outb + (size_t)which * per
                    + (((size_t)(b * Hn + h) * Tn + t0g + row) * Dn) + d;
                *(ushort8_t*)dst = *(const ushort8_t*)&Lc[row * 80 + c8];
            }
        }
    } else {
        #pragma unroll
        for (int i = 0; i < MF; ++i) {
            #pragma unroll
            for (int r = 0; r < 4; ++r) {
                int mrow = m0 + wave * (MTILE / 4) + i * 16 + g * 4 + r;
                #pragma unroll
                for (int j = 0; j < 4; ++j)
                    outf[(size_t)mrow * Cn + n0 + j * 16 + m] = acc[i][j][r];
            }
        }
    }
}

// ---------------------------------------------------------------------------
// Flash attention via S^T, no-max softmax, bf16 MFMA (round-7 kernel, 64.3us,
// + round-9 interleaved-qt grid for CU load balance).
// Q-tile 128, 512 threads (8 waves x 16 q). K-tile 64, double-buffered
// global_load_lds staging, lane-linear segments. Ps aliases dead Q strip.
// ---------------------------------------------------------------------------
__global__ __launch_bounds__(512, 6)
void attn_mfma(const ushort_t* __restrict__ Q, const ushort_t* __restrict__ K,
               const ushort_t* __restrict__ V, ushort_t* __restrict__ Y,
               const ushort_t* __restrict__ zb)
{
    __shared__ __align__(16) ushort_t QPs[16][512];    // Q tile, then reused as P^T
    __shared__ __align__(16) ushort_t Ks[2][8][512];   // [buf][(ktile t, kc)]
    __shared__ __align__(16) ushort_t Vs[2][6][512];   // [buf][(dtile t, kc)]

    const int id   = blockIdx.x;
    const int kk   = id / 48;
    const int bh   = id - kk * 48;
    const int QT   = (kk & 1) ? (kk >> 1) : (15 - (kk >> 1));   // interleave big/small
    const int tid  = threadIdx.x;
    const int wave = tid >> 6;       // 0..7
    const int lane = tid & 63;
    const int m    = lane & 15;
    const int g    = lane >> 4;
    const int q0   = QT * 128;
    const int nkt  = 2 * QT + 2;     // 64-row K tiles to process

    const ushort_t* Qp = Q + (size_t)bh * Tn * Dn;
    const ushort_t* Kp = K + (size_t)bh * Tn * Dn;
    const ushort_t* Vp = V + (size_t)bh * Dn * Tn;     // [48][T]

    // ---- Q staging: wave w stages segs 2w,2w+1 (rows q0+w*16+m); pad -> zeros ----
    {
        const char* qrp = (const char*)(Qp + (size_t)(q0 + wave * 16 + m) * Dn);
        gload16(&QPs[wave * 2 + 0][0], qrp + g * 16);
        gload16(&QPs[wave * 2 + 1][0], (g < 2) ? (qrp + 64 + g * 16) : (const char*)zb);
    }

    // ---- per-lane K/V staging pointers (wave w owns K seg w; V seg w for w<6) ----
    const bool  kpad = ((wave & 1) == 1) && (g >= 2);
    const char* kptr = kpad ? (const char*)zb
        : (const char*)(Kp + (size_t)((wave >> 1) * 16 + m) * Dn) + (wave & 1) * 64 + g * 16;
    const int   kadv = kpad ? 0 : 64 * Dn * 2;         // 64 K-rows per tile
    const char* vptr = (const char*)(Vp + (size_t)((wave >> 1) * 16 + m) * Tn)
                       + (wave & 1) * 64 + g * 16;     // valid only for wave<6
    const int   vadv = 64 * 2;                         // 64 V^T-cols per tile

    // prologue: stage K/V tile 0 into buf 0
    gload16(&Ks[0][wave][0], kptr); kptr += kadv;
    if (wave < 6) { gload16(&Vs[0][wave][0], vptr); vptr += vadv; }
    __syncthreads();   // drains vmcnt -> Q + tile0 ready

    // loop-invariant B-fragments (Q); QPs strip (wave-private) then dead -> P^T
    short8 bq[2];
    bq[0] = *(const short8*)&QPs[wave * 2 + 0][lane * 8];
    bq[1] = *(const short8*)&QPs[wave * 2 + 1][lane * 8];

    floatx4 acc[3];
    #pragma unroll
    for (int t = 0; t < 3; ++t) acc[t] = (floatx4){0.f, 0.f, 0.f, 0.f};
    float l_tot = 0.f;
    const int qrow  = q0 + wave * 16 + m;    // this lane's global query row
    const int qwmin = q0 + wave * 16;        // wave's min query row
    const int qwmax = qwmin + 15;            // wave's max query row

    for (int jt = 0; jt < nkt; ++jt) {
        const int cur = jt & 1;
        const int j0  = jt * 64;
        // issue async staging for tile jt+1 (overlaps this tile's compute)
        if (jt + 1 < nkt) {
            gload16(&Ks[cur ^ 1][wave][0], kptr); kptr += kadv;
            if (wave < 6) { gload16(&Vs[cur ^ 1][wave][0], vptr); vptr += vadv; }
        }

        if (j0 <= qwmax) {   // wave-uniform: at least one unmasked element
            // ---- S^T = K Q^T : D[m=j (4 tiles)][n=q] ----
            floatx4 s[4];
            #pragma unroll
            for (int t = 0; t < 4; ++t) {
                s[t] = (floatx4){0.f, 0.f, 0.f, 0.f};
                #pragma unroll
                for (int kc = 0; kc < 2; ++kc) {
                    short8 ak = *(const short8*)&Ks[cur][t * 2 + kc][lane * 8];
                    s[t] = __builtin_amdgcn_mfma_f32_16x16x32_bf16(ak, bq[kc], s[t], 0, 0, 0);
                }
            }

            // ---- mask (only if tile straddles diagonal) + exp2 + partial sum ----
            float p[4][4];
            float lsum = 0.f;
            if (j0 + 63 > qwmin) {
                #pragma unroll
                for (int t = 0; t < 4; ++t)
                    #pragma unroll
                    for (int r = 0; r < 4; ++r) {
                        int j = j0 + t * 16 + g * 4 + r;
                        float v = (j <= qrow) ? s[t][r] : -1e30f;
                        float e = __builtin_amdgcn_exp2f(v);
                        p[t][r] = e; lsum += e;
                    }
            } else {
                #pragma unroll
                for (int t = 0; t < 4; ++t)
                    #pragma unroll
                    for (int r = 0; r < 4; ++r) {
                        float e = __builtin_amdgcn_exp2f(s[t][r]);
                        p[t][r] = e; lsum += e;
                    }
            }
            lsum += __shfl_xor(lsum, 16);
            lsum += __shfl_xor(lsum, 32);
            l_tot += lsum;

            // ---- store P^T in B-frag order into the (dead) Q strip ----
            #pragma unroll
            for (int t = 0; t < 4; ++t) {
                uint2 w2;
                w2.x = pack_trunc(p[t][0], p[t][1]);
                w2.y = pack_trunc(p[t][2], p[t][3]);
                *(uint2*)&QPs[wave * 2 + (t >> 1)]
                             [(2 * (t & 1) + (g >> 1)) * 128 + m * 8 + (g & 1) * 4] = w2;
            }
            // wave-private strip: drain this wave's LDS writes, no barrier needed
            asm volatile("s_waitcnt lgkmcnt(0)" ::: "memory");

            // ---- O^T += V^T P^T : D[m=d (3 tiles)][n=q] ----
            #pragma unroll
            for (int kc = 0; kc < 2; ++kc) {
                short8 bp = *(const short8*)&QPs[wave * 2 + kc][lane * 8];
                #pragma unroll
                for (int t = 0; t < 3; ++t) {
                    short8 av = *(const short8*)&Vs[cur][t * 2 + kc][lane * 8];
                    acc[t] = __builtin_amdgcn_mfma_f32_16x16x32_bf16(av, bp, acc[t], 0, 0, 0);
                }
            }
        }

        __syncthreads();   // next tile staged (vmcnt drain) + cur-buf reads done
    }

    // ---- epilogue: lane holds O^T[d = t*16+g*4+r][qrow]; normalize, store ----
    const float inv = 1.0f / l_tot;
    const int b = bh / Hn;
    const int h = bh - b * Hn;
    ushort_t* yp = Y + ((size_t)(b * Tn + qrow)) * Cn + h * Dn;
    #pragma unroll
    for (int t = 0; t < 3; ++t) {
        ushort4 o;
        o.x = f2bf(acc[t][0] * inv);
        o.y = f2bf(acc[t][1] * inv);
        o.z = f2bf(acc[t][2] * inv);
        o.w = f2bf(acc[t][3] * inv);
        *(ushort4*)&yp[t * 16 + g * 4] = o;
    }
}

// ---------------------------------------------------------------------------
extern "C" void kernel_launch(void* const* d_in, const int* in_sizes, int n_in,
                              void* d_out, int out_size, void* d_ws, size_t ws_size,
                              hipStream_t stream)
{
    const float* x      = (const float*)d_in[0];   // [B,T,C]
    const float* w_qkv  = (const float*)d_in[1];   // [3C,C]
    const float* w_proj = (const float*)d_in[2];   // [C,C]
    float* out = (float*)d_out;                    // [B,T,C] fp32

    const size_t per = (size_t)Bn * Hn * Tn * Dn;  // 4,718,592

    ushort_t* xb  = (ushort_t*)d_ws;               // 8192*576
    ushort_t* wqb = xb  + (size_t)Mn * Cn;         // 1728*576
    ushort_t* wpb = wqb + (size_t)3 * Cn * Cn;     // 576*576
    ushort_t* qkv = wpb + (size_t)Cn * Cn;         // 3*per (q | k | v^T)
    ushort_t* yb  = qkv + 3 * per;                 // 8192*576
    ushort_t* zb  = yb  + (size_t)Mn * Cn;         // 256 B of zeros (Q/K pad source)

    hipMemsetAsync(zb, 0, 256, stream);

    // fused casts (fp32 -> bf16)
    const int na4 = Mn * Cn / 4, nb4 = 3 * Cn * Cn / 4, nc4 = Cn * Cn / 4;
    cast3<<<dim3((na4 + nb4 + nc4 + 255) / 256), dim3(256), 0, stream>>>(
        x, xb, na4, w_qkv, wqb, nb4, w_proj, wpb, nc4);

    // QKV GEMM (M=8192, N=1728): 864 blocks = 8 XCD x (32/8 m-groups x 27 n)
    gemm_mfma<0, 256><<<dim3((Mn / 256) * 27), dim3(256), 0, stream>>>(xb, wqb, qkv, nullptr);

    // causal attention (ALiBi bias is exactly zero on the unmasked region)
    attn_mfma<<<dim3((Tn / 128) * Bn * Hn), dim3(512), 0, stream>>>(
        qkv, qkv + per, qkv + 2 * per, yb, zb);

    // output projection (M=8192, N=576) -> fp32: 576 blocks, XCD-swizzled
    gemm_mfma<1, 128><<<dim3((Mn / 128) * 9), dim3(256), 0, stream>>>(yb, wpb, nullptr, out);
}

// Round 2
// 163.396 us; speedup vs baseline: 1.1373x; 1.1256x over previous
//
#include <hip/hip_runtime.h>
#include <math.h>

// Problem constants (B=4, T=2048, C=576, H=12, D=48)
#define Bn 4
#define Tn 2048
#define Cn 576
#define Hn 12
#define Dn 48
#define Mn (Bn*Tn)          // 8192 rows
#define NPAD 1792           // QKV N padded to 7*256 (pad rows read adjacent ws, never written)

// log2(e) / sqrt(48) — folded into q so attention uses exp2 directly
#define QSCALE (1.4426950408889634f * 0.14433756729740643f)

typedef short  short8  __attribute__((ext_vector_type(8)));   // 8 bf16 (4 VGPRs)
typedef float  floatx4 __attribute__((ext_vector_type(4)));   // MFMA acc
typedef unsigned short ushort_t;
typedef unsigned short ushort8_t __attribute__((ext_vector_type(8))); // 16B

static __device__ __forceinline__ unsigned short f2bf(float f) {
    union { float f; unsigned int u; } v; v.f = f;
    unsigned int r = v.u + 0x7FFFu + ((v.u >> 16) & 1u);   // round-to-nearest-even
    return (unsigned short)(r >> 16);
}

// truncation-pack two fp32 -> packed bf16x2 (P >= 0, rel err <= 2^-8)
static __device__ __forceinline__ unsigned int pack_trunc(float a, float b) {
    union { float f; unsigned int u; } ua, ub; ua.f = a; ub.f = b;
    return (ua.u >> 16) | (ub.u & 0xFFFF0000u);
}

// async global->LDS, 16B per lane; lane l's data lands at lds + l*16 (lane-linear)
static __device__ __forceinline__ void gload16(void* lds, const void* g) {
    __builtin_amdgcn_global_load_lds(
        (const __attribute__((address_space(1))) void*)g,
        (__attribute__((address_space(3))) void*)lds, 16, 0, 0);
}

// counted vmcnt (T4): literal-dispatched
template<int N> static __device__ __forceinline__ void vmgate() {
    if constexpr (N == 0)      asm volatile("s_waitcnt vmcnt(0)" ::: "memory");
    else if constexpr (N == 4) asm volatile("s_waitcnt vmcnt(4)" ::: "memory");
    else if constexpr (N == 8) asm volatile("s_waitcnt vmcnt(8)" ::: "memory");
    // N == -1: no gate
}
static __device__ __forceinline__ void lgk0() {
    asm volatile("s_waitcnt lgkmcnt(0)" ::: "memory");
}
static __device__ __forceinline__ void barrier_fence() {
    asm volatile("" ::: "memory");
    __builtin_amdgcn_s_barrier();
    asm volatile("" ::: "memory");
}

// old-style counted waits for the MODE-1 (proj) kernel
template<int N> static __device__ __forceinline__ void wait_vm_lg() {
    if constexpr (N == 0)
        asm volatile("s_waitcnt vmcnt(0) lgkmcnt(0)" ::: "memory");
    else if constexpr (N == 3)
        asm volatile("s_waitcnt vmcnt(3) lgkmcnt(0)" ::: "memory");
    else if constexpr (N == 6)
        asm volatile("s_waitcnt vmcnt(6) lgkmcnt(0)" ::: "memory");
    else
        static_assert(N == -12345, "unsupported waitcnt immediate");
}

// ---------------------------------------------------------------------------
// fused fp32 -> bf16 cast of all three inputs (one launch)
// ---------------------------------------------------------------------------
__global__ __launch_bounds__(256)
void cast3(const float* __restrict__ a, ushort_t* __restrict__ oa, int na4,
           const float* __restrict__ b, ushort_t* __restrict__ ob, int nb4,
           const float* __restrict__ c, ushort_t* __restrict__ oc, int nc4)
{
    int i = blockIdx.x * 256 + threadIdx.x;
    const float* src; ushort_t* dst; int idx;
    if (i < na4)                  { src = a; dst = oa; idx = i; }
    else if (i < na4 + nb4)       { src = b; dst = ob; idx = i - na4; }
    else if (i < na4 + nb4 + nc4) { src = c; dst = oc; idx = i - na4 - nb4; }
    else return;
    float4 v = ((const float4*)src)[idx];
    ushort4 o;
    o.x = f2bf(v.x); o.y = f2bf(v.y); o.z = f2bf(v.z); o.w = f2bf(v.w);
    ((ushort4*)dst)[idx] = o;
}

// ---------------------------------------------------------------------------
// ROUND-10 QKV GEMM: 8-phase 256x256 schedule (T2+T3+T4+T5 port).
// out = A[8192,576] @ W[1792(pad),576]^T, BK=64, 8 waves (2M x 4N), 512 thr.
// Half-tile stream (K-split): per K-tile t: ht 4t+0 = A[256][k0..k0+31],
// 4t+1 = B[256][k0..31], 4t+2 = A[k1], 4t+3 = B[k1].  16KB each.
// LDS ring: 8 slots x 16KB = 128KB (2 K-tiles).  Stagger S=6 half-tiles.
// Per phase: {ds_read frag subtile || stage 1 ht} barrier; lgkmcnt(0);
// setprio(1) 16 MFMA setprio(0); [vm gate ph1/ph3] barrier.
// Steady-state gate vmcnt(8) (= 4 ht in flight), tail 4 -> 0. Never vmcnt(0)
// mid-loop.  Safety: stage of ht h issues >= 1 full phase after last read of
// ht h-8 (K-split half-tiles are last-read in their own phase); DMA-landed
// is enforced by the counted gates (all waves issue identical load streams).
// LDS [256 rows][32k] rows of 64B: a frag ds_read_b128 is a bijection onto a
// contiguous 1KB span -> 2-way banking (free), no swizzle needed.
// Grid: 224 blocks = 8 XCD x (4 m x 7 n) -> exactly 1 block/CU, no tail.
// ---------------------------------------------------------------------------
__global__ __launch_bounds__(512)
void gemm_qkv(const ushort_t* __restrict__ A, const ushort_t* __restrict__ W,
              ushort_t* __restrict__ outb)
{
    __shared__ __align__(16) ushort_t Ls[8][8192];   // 8 x 16KB ring

    const int tid  = threadIdx.x;
    const int wave = tid >> 6;
    const int lane = tid & 63;
    const int m    = lane & 15;
    const int g    = lane >> 4;
    const int wr   = wave >> 2;      // m-half 0..1
    const int wn   = wave & 3;       // n-quarter 0..3

    const int bid  = blockIdx.x;
    const int xcd  = bid & 7;
    const int slot = bid >> 3;       // 0..27
    const int ng   = slot % 7;
    const int mg   = xcd + 8 * (slot / 7);
    const int m0   = mg * 256;
    const int n0g  = ng * 256;

    // ---- staging pointers: wave w, instr i covers rows (w*2+i)*16 + (lane>>2),
    //      16B chunk (lane&3) of the 64B k-slice; advance 64B per stage of a kind
    const int srow = lane >> 2;
    const int schk = (lane & 3) * 16;
    const char* aS0 = (const char*)A + (size_t)(m0  + (wave*2+0)*16 + srow) * (Cn*2) + schk;
    const char* aS1 = (const char*)A + (size_t)(m0  + (wave*2+1)*16 + srow) * (Cn*2) + schk;
    const char* bS0 = (const char*)W + (size_t)(n0g + (wave*2+0)*16 + srow) * (Cn*2) + schk;
    const char* bS1 = (const char*)W + (size_t)(n0g + (wave*2+1)*16 + srow) * (Cn*2) + schk;

    // ---- LDS read offsets (bytes): frag row -> row*64 + g*16; + mf/nf*1024
    const int aoff = (wr * 128 + m) * 64 + g * 16;
    const int boff = (wn * 64  + m) * 64 + g * 16;

    floatx4 acc[8][4];
    #pragma unroll
    for (int i = 0; i < 8; ++i)
        #pragma unroll
        for (int j = 0; j < 4; ++j)
            acc[i][j] = (floatx4){0.f, 0.f, 0.f, 0.f};

    short8 af[8], bf01[2], bf23[2];

    auto stageA = [&](int s) {
        gload16(&Ls[s][(wave*2+0)*512], aS0); aS0 += 64;
        gload16(&Ls[s][(wave*2+1)*512], aS1); aS1 += 64;
    };
    auto stageB = [&](int s) {
        gload16(&Ls[s][(wave*2+0)*512], bS0); bS0 += 64;
        gload16(&Ls[s][(wave*2+1)*512], bS1); bS1 += 64;
    };
    auto loadA = [&](int s) {
        const char* base = (const char*)&Ls[s][0] + aoff;
        #pragma unroll
        for (int mf = 0; mf < 8; ++mf) af[mf] = *(const short8*)(base + mf * 1024);
    };
    auto loadB = [&](int s, int nf0, short8 (&bf)[2]) {
        const char* base = (const char*)&Ls[s][0] + boff;
        bf[0] = *(const short8*)(base + (nf0 + 0) * 1024);
        bf[1] = *(const short8*)(base + (nf0 + 1) * 1024);
    };
    auto mfma16 = [&](short8 (&bf)[2], int nf0) {
        __builtin_amdgcn_s_setprio(1);
        #pragma unroll
        for (int mf = 0; mf < 8; ++mf) {
            acc[mf][nf0]     = __builtin_amdgcn_mfma_f32_16x16x32_bf16(af[mf], bf[0], acc[mf][nf0],     0, 0, 0);
            acc[mf][nf0 + 1] = __builtin_amdgcn_mfma_f32_16x16x32_bf16(af[mf], bf[1], acc[mf][nf0 + 1], 0, 0, 0);
        }
        __builtin_amdgcn_s_setprio(0);
    };

    // ---- prologue: stage ht 0..5 (A,B,A,B,A,B), gate so ht0,1 landed ----
    stageA(0); stageB(1); stageA(2); stageB(3); stageA(4); stageB(5);
    vmgate<8>();
    barrier_fence();

    // One K-tile = 4 phases.  s0 = slot of this tile's first ht (0 or 4).
    #define QKV_TILE(s0, d0, d1, d2, d3, G1m, G3m) do {                         \
        constexpr int A0 = (s0) & 7,      B0 = ((s0)+1) & 7;                    \
        constexpr int A1 = ((s0)+2) & 7,  B1 = ((s0)+3) & 7;                    \
        constexpr int S0 = ((s0)+6) & 7,  S1 = ((s0)+7) & 7;                    \
        constexpr int S2 = ((s0)+8) & 7,  S3 = ((s0)+9) & 7;                    \
        /* ph0: A(k0) + B(n01,k0) */                                            \
        loadA(A0); loadB(B0, 0, bf01);                                          \
        if (d0) stageA(S0);                                                     \
        barrier_fence(); lgk0();                                                \
        mfma16(bf01, 0);                                                        \
        barrier_fence();                                                        \
        /* ph1: B(n23,k0) */                                                    \
        loadB(B0, 2, bf23);                                                     \
        if (d1) stageB(S1);                                                     \
        barrier_fence(); lgk0();                                                \
        mfma16(bf23, 2);                                                        \
        vmgate<G1m>();                                                          \
        barrier_fence();                                                        \
        /* ph2: A(k1) + B(n01,k1) */                                            \
        loadA(A1); loadB(B1, 0, bf01);                                          \
        if (d2) stageA(S2);                                                     \
        barrier_fence(); lgk0();                                                \
        mfma16(bf01, 0);                                                        \
        barrier_fence();                                                        \
        /* ph3: B(n23,k1) */                                                    \
        loadB(B1, 2, bf23);                                                     \
        if (d3) stageB(S3);                                                     \
        barrier_fence(); lgk0();                                                \
        mfma16(bf23, 2);                                                        \
        vmgate<G3m>();                                                          \
        barrier_fence();                                                        \
    } while (0)

    // tiles 0..5 (steady state), then 6 (last full-stage), 7 (partial), 8 (drain)
    #pragma unroll 1
    for (int tt = 0; tt < 3; ++tt) {
        QKV_TILE(0, 1, 1, 1, 1, 8, 8);
        QKV_TILE(4, 1, 1, 1, 1, 8, 8);
    }
    QKV_TILE(0, 1, 1, 1, 1, 8, 8);   // t=6 (stages ht 30..33)
    QKV_TILE(4, 1, 1, 0, 0, 8, 4);   // t=7 (stages ht 34,35)
    QKV_TILE(0, 0, 0, 0, 0, 0, -1);  // t=8 (drain; vm(0) before its k1 reads)
    #undef QKV_TILE

    // ---- epilogue: acc[mf][nf] row = m0+wr*128+mf*16+g*4+r, col(n-local) =
    //      wn*64+nf*16+m.  Two contiguous n-halves of 128; v-halves staged
    //      transposed for [B,H,48,T] coalesced writes. ----
    const size_t per = (size_t)Bn * Hn * Tn * Dn;
    const int b  = m0 >> 11;
    const int t0 = m0 & 2047;
    ushort_t* Lc = (ushort_t*)&Ls[0][0];

    #pragma unroll
    for (int h2 = 0; h2 < 2; ++h2) {
        const int  nbase = n0g + h2 * 128;     // first global n of this half
        const bool vmode = (nbase >= 1152);    // 1152 = 9*128: half-uniform
        if ((wn >> 1) == h2) {
            if (!vmode) {
                // row-major Lq[256][136]
                #pragma unroll
                for (int mf = 0; mf < 8; ++mf)
                    #pragma unroll
                    for (int nf = 0; nf < 4; ++nf) {
                        const int  nfb = n0g + wn * 64 + nf * 16;   // frag n base
                        const float sc = (nfb < 576) ? QSCALE : 1.0f;
                        const int col = (wn & 1) * 64 + nf * 16 + m;
                        const int rb  = wr * 128 + mf * 16 + g * 4;
                        #pragma unroll
                        for (int r = 0; r < 4; ++r)
                            Lc[(rb + r) * 136 + col] = f2bf(acc[mf][nf][r] * sc);
                    }
            } else {
                // transposed Lv[128][264]
                #pragma unroll
                for (int mf = 0; mf < 8; ++mf)
                    #pragma unroll
                    for (int nf = 0; nf < 4; ++nf) {
                        const int col = (wn & 1) * 64 + nf * 16 + m;
                        const int rb  = wr * 128 + mf * 16 + g * 4;
                        ushort4 pk;
                        pk.x = f2bf(acc[mf][nf][0]); pk.y = f2bf(acc[mf][nf][1]);
                        pk.z = f2bf(acc[mf][nf][2]); pk.w = f2bf(acc[mf][nf][3]);
                        *(ushort4*)&Lc[col * 264 + rb] = pk;
                    }
            }
        }
        __syncthreads();
        if (!vmode) {
            // q/k: [B,H,T,48]; 16B chunks along d (8|48 -> no head straddle)
            #pragma unroll
            for (int it = 0; it < 8; ++it) {
                const int c   = tid + it * 512;
                const int row = c >> 4;
                const int c8  = (c & 15) * 8;
                const int n   = nbase + c8;
                const int which = (n >= 576);
                const int nn  = n - which * 576;
                const int h   = nn / 48, d = nn - h * 48;
                ushort_t* dst = outb + (size_t)which * per
                    + ((size_t)(b * Hn + h) * Tn + t0 + row) * Dn + d;
                *(ushort8_t*)dst = *(const ushort8_t*)&Lc[row * 136 + c8];
            }
        } else {
            // v: [B,H,48,T]; 16B chunks along t; skip pad cols (n >= 1728)
            #pragma unroll
            for (int it = 0; it < 8; ++it) {
                const int c   = tid + it * 512;
                const int col = c >> 5;
                const int rc  = (c & 31) * 8;
                const int n   = nbase + col;
                if (n < 1728) {
                    const int dd = n - 1152;
                    const int h  = dd / 48, d = dd - h * 48;
                    ushort_t* dst = outb + 2 * per
                        + ((size_t)(b * Hn + h) * Dn + d) * Tn + t0 + rc;
                    *(ushort8_t*)dst = *(const ushort8_t*)&Lc[col * 264 + rc];
                }
            }
        }
        __syncthreads();
    }
}

// ---------------------------------------------------------------------------
// MFMA bf16 GEMM (proj only now): out = A[M,576] @ W[N,576]^T, fp32 out.
// 4-buffer / 3-ahead counted-vmcnt pipeline (round-10).
// ---------------------------------------------------------------------------
template<int MODE, int MTILE>
__global__ __launch_bounds__(256)
void gemm_mfma(const ushort_t* __restrict__ A, const ushort_t* __restrict__ W,
               ushort_t* __restrict__ outb, float* __restrict__ outf)
{
    constexpr int SA   = MTILE / 16;      // A segments
    constexpr int NSEG = SA + 4;          // + B segments (NTILE=64)
    constexpr int PW   = NSEG / 4;        // staging loads per wave per K-step
    constexpr int MF   = MTILE / 64;      // m-frags per wave
    constexpr int NB   = 9;
    constexpr int NST  = Cn / 32;         // 18 K-steps
    constexpr int AH   = 3;               // prefetch depth (steps ahead)
    constexpr int NBUF = 4;               // AH+1 ring buffers
    __shared__ __align__(16) ushort_t Ls[NBUF][NSEG][512];

    const int tid  = threadIdx.x;
    const int wave = tid >> 6;
    const int lane = tid & 63;
    const int m    = lane & 15;
    const int g    = lane >> 4;
    const int bid  = blockIdx.x;
    const int xcd  = bid & 7;
    const int slot = bid >> 3;
    const int n0   = (slot % NB) * 64;
    const int m0   = (xcd + 8 * (slot / NB)) * MTILE;

    floatx4 acc[MF][4];
    #pragma unroll
    for (int i = 0; i < MF; ++i)
        #pragma unroll
        for (int j = 0; j < 4; ++j)
            acc[i][j] = (floatx4){0.f, 0.f, 0.f, 0.f};

    const char* gp[PW];
    int         si[PW];
    #pragma unroll
    for (int i = 0; i < PW; ++i) {
        int s = wave + i * 4;
        si[i] = s;
        gp[i] = (s < SA)
            ? (const char*)(A + (size_t)(m0 + s * 16 + m) * Cn + g * 8)
            : (const char*)(W + (size_t)(n0 + (s - SA) * 16 + m) * Cn + g * 8);
    }

    #pragma unroll
    for (int s = 0; s < AH; ++s)
        #pragma unroll
        for (int i = 0; i < PW; ++i) { gload16(&Ls[s][si[i]][0], gp[i]); gp[i] += 64; }
    wait_vm_lg<(AH - 1) * PW>();
    __builtin_amdgcn_s_barrier();

    for (int j = 0; j < NST; ++j) {
        if (j + AH < NST) {
            #pragma unroll
            for (int i = 0; i < PW; ++i) {
                gload16(&Ls[(j + AH) & (NBUF - 1)][si[i]][0], gp[i]);
                gp[i] += 64;
            }
        }
        const int buf = j & (NBUF - 1);
        short8 bf4[4];
        #pragma unroll
        for (int jj = 0; jj < 4; ++jj)
            bf4[jj] = *(const short8*)&Ls[buf][SA + jj][lane * 8];
        #pragma unroll
        for (int i = 0; i < MF; ++i) {
            short8 afr = *(const short8*)&Ls[buf][wave * MF + i][lane * 8];
            #pragma unroll
            for (int jj = 0; jj < 4; ++jj)
                acc[i][jj] = __builtin_amdgcn_mfma_f32_16x16x32_bf16(afr, bf4[jj], acc[i][jj], 0, 0, 0);
        }
        if (j < NST - AH)        wait_vm_lg<(AH - 1) * PW>();
        else if (j == NST - AH)  wait_vm_lg<(AH - 2) * PW>();
        else                     wait_vm_lg<0>();
        __builtin_amdgcn_s_barrier();
    }

    #pragma unroll
    for (int i = 0; i < MF; ++i) {
        #pragma unroll
        for (int r = 0; r < 4; ++r) {
            int mrow = m0 + wave * (MTILE / 4) + i * 16 + g * 4 + r;
            #pragma unroll
            for (int j = 0; j < 4; ++j)
                outf[(size_t)mrow * Cn + n0 + j * 16 + m] = acc[i][j][r];
        }
    }
}

// ---------------------------------------------------------------------------
// Flash attention via S^T, no-max softmax, bf16 MFMA (round-7 kernel, 64.3us,
// + round-9 interleaved-qt grid for CU load balance).
// ---------------------------------------------------------------------------
__global__ __launch_bounds__(512, 6)
void attn_mfma(const ushort_t* __restrict__ Q, const ushort_t* __restrict__ K,
               const ushort_t* __restrict__ V, ushort_t* __restrict__ Y,
               const ushort_t* __restrict__ zb)
{
    __shared__ __align__(16) ushort_t QPs[16][512];    // Q tile, then reused as P^T
    __shared__ __align__(16) ushort_t Ks[2][8][512];   // [buf][(ktile t, kc)]
    __shared__ __align__(16) ushort_t Vs[2][6][512];   // [buf][(dtile t, kc)]

    const int id   = blockIdx.x;
    const int kk   = id / 48;
    const int bh   = id - kk * 48;
    const int QT   = (kk & 1) ? (kk >> 1) : (15 - (kk >> 1));   // interleave big/small
    const int tid  = threadIdx.x;
    const int wave = tid >> 6;       // 0..7
    const int lane = tid & 63;
    const int m    = lane & 15;
    const int g    = lane >> 4;
    const int q0   = QT * 128;
    const int nkt  = 2 * QT + 2;     // 64-row K tiles to process

    const ushort_t* Qp = Q + (size_t)bh * Tn * Dn;
    const ushort_t* Kp = K + (size_t)bh * Tn * Dn;
    const ushort_t* Vp = V + (size_t)bh * Dn * Tn;     // [48][T]

    {
        const char* qrp = (const char*)(Qp + (size_t)(q0 + wave * 16 + m) * Dn);
        gload16(&QPs[wave * 2 + 0][0], qrp + g * 16);
        gload16(&QPs[wave * 2 + 1][0], (g < 2) ? (qrp + 64 + g * 16) : (const char*)zb);
    }

    const bool  kpad = ((wave & 1) == 1) && (g >= 2);
    const char* kptr = kpad ? (const char*)zb
        : (const char*)(Kp + (size_t)((wave >> 1) * 16 + m) * Dn) + (wave & 1) * 64 + g * 16;
    const int   kadv = kpad ? 0 : 64 * Dn * 2;         // 64 K-rows per tile
    const char* vptr = (const char*)(Vp + (size_t)((wave >> 1) * 16 + m) * Tn)
                       + (wave & 1) * 64 + g * 16;     // valid only for wave<6
    const int   vadv = 64 * 2;                         // 64 V^T-cols per tile

    gload16(&Ks[0][wave][0], kptr); kptr += kadv;
    if (wave < 6) { gload16(&Vs[0][wave][0], vptr); vptr += vadv; }
    __syncthreads();   // drains vmcnt -> Q + tile0 ready

    short8 bq[2];
    bq[0] = *(const short8*)&QPs[wave * 2 + 0][lane * 8];
    bq[1] = *(const short8*)&QPs[wave * 2 + 1][lane * 8];

    floatx4 acc[3];
    #pragma unroll
    for (int t = 0; t < 3; ++t) acc[t] = (floatx4){0.f, 0.f, 0.f, 0.f};
    float l_tot = 0.f;
    const int qrow  = q0 + wave * 16 + m;
    const int qwmin = q0 + wave * 16;
    const int qwmax = qwmin + 15;

    for (int jt = 0; jt < nkt; ++jt) {
        const int cur = jt & 1;
        const int j0  = jt * 64;
        if (jt + 1 < nkt) {
            gload16(&Ks[cur ^ 1][wave][0], kptr); kptr += kadv;
            if (wave < 6) { gload16(&Vs[cur ^ 1][wave][0], vptr); vptr += vadv; }
        }

        if (j0 <= qwmax) {
            floatx4 s[4];
            #pragma unroll
            for (int t = 0; t < 4; ++t) {
                s[t] = (floatx4){0.f, 0.f, 0.f, 0.f};
                #pragma unroll
                for (int kc = 0; kc < 2; ++kc) {
                    short8 ak = *(const short8*)&Ks[cur][t * 2 + kc][lane * 8];
                    s[t] = __builtin_amdgcn_mfma_f32_16x16x32_bf16(ak, bq[kc], s[t], 0, 0, 0);
                }
            }

            float p[4][4];
            float lsum = 0.f;
            if (j0 + 63 > qwmin) {
                #pragma unroll
                for (int t = 0; t < 4; ++t)
                    #pragma unroll
                    for (int r = 0; r < 4; ++r) {
                        int j = j0 + t * 16 + g * 4 + r;
                        float v = (j <= qrow) ? s[t][r] : -1e30f;
                        float e = __builtin_amdgcn_exp2f(v);
                        p[t][r] = e; lsum += e;
                    }
            } else {
                #pragma unroll
                for (int t = 0; t < 4; ++t)
                    #pragma unroll
                    for (int r = 0; r < 4; ++r) {
                        float e = __builtin_amdgcn_exp2f(s[t][r]);
                        p[t][r] = e; lsum += e;
                    }
            }
            lsum += __shfl_xor(lsum, 16);
            lsum += __shfl_xor(lsum, 32);
            l_tot += lsum;

            #pragma unroll
            for (int t = 0; t < 4; ++t) {
                uint2 w2;
                w2.x = pack_trunc(p[t][0], p[t][1]);
                w2.y = pack_trunc(p[t][2], p[t][3]);
                *(uint2*)&QPs[wave * 2 + (t >> 1)]
                             [(2 * (t & 1) + (g >> 1)) * 128 + m * 8 + (g & 1) * 4] = w2;
            }
            asm volatile("s_waitcnt lgkmcnt(0)" ::: "memory");

            #pragma unroll
            for (int kc = 0; kc < 2; ++kc) {
                short8 bp = *(const short8*)&QPs[wave * 2 + kc][lane * 8];
                #pragma unroll
                for (int t = 0; t < 3; ++t) {
                    short8 av = *(const short8*)&Vs[cur][t * 2 + kc][lane * 8];
                    acc[t] = __builtin_amdgcn_mfma_f32_16x16x32_bf16(av, bp, acc[t], 0, 0, 0);
                }
            }
        }

        __syncthreads();
    }

    const float inv = 1.0f / l_tot;
    const int b = bh / Hn;
    const int h = bh - b * Hn;
    ushort_t* yp = Y + ((size_t)(b * Tn + qrow)) * Cn + h * Dn;
    #pragma unroll
    for (int t = 0; t < 3; ++t) {
        ushort4 o;
        o.x = f2bf(acc[t][0] * inv);
        o.y = f2bf(acc[t][1] * inv);
        o.z = f2bf(acc[t][2] * inv);
        o.w = f2bf(acc[t][3] * inv);
        *(ushort4*)&yp[t * 16 + g * 4] = o;
    }
}

// ---------------------------------------------------------------------------
extern "C" void kernel_launch(void* const* d_in, const int* in_sizes, int n_in,
                              void* d_out, int out_size, void* d_ws, size_t ws_size,
                              hipStream_t stream)
{
    const float* x      = (const float*)d_in[0];   // [B,T,C]
    const float* w_qkv  = (const float*)d_in[1];   // [3C,C]
    const float* w_proj = (const float*)d_in[2];   // [C,C]
    float* out = (float*)d_out;                    // [B,T,C] fp32

    const size_t per = (size_t)Bn * Hn * Tn * Dn;  // 4,718,592

    ushort_t* xb  = (ushort_t*)d_ws;               // 8192*576
    ushort_t* wqb = xb  + (size_t)Mn * Cn;         // 1728*576 (+64 pad rows read into wpb)
    ushort_t* wpb = wqb + (size_t)3 * Cn * Cn;     // 576*576
    ushort_t* qkv = wpb + (size_t)Cn * Cn;         // 3*per (q | k | v^T)
    ushort_t* yb  = qkv + 3 * per;                 // 8192*576
    ushort_t* zb  = yb  + (size_t)Mn * Cn;         // 256 B of zeros (Q/K pad source)

    hipMemsetAsync(zb, 0, 256, stream);

    // fused casts (fp32 -> bf16)
    const int na4 = Mn * Cn / 4, nb4 = 3 * Cn * Cn / 4, nc4 = Cn * Cn / 4;
    cast3<<<dim3((na4 + nb4 + nc4 + 255) / 256), dim3(256), 0, stream>>>(
        x, xb, na4, w_qkv, wqb, nb4, w_proj, wpb, nc4);

    // QKV GEMM (M=8192, N=1792 padded): 224 blocks = 1/CU, 8-phase schedule
    gemm_qkv<<<dim3(224), dim3(512), 0, stream>>>(xb, wqb, qkv);

    // causal attention (ALiBi bias is exactly zero on the unmasked region)
    attn_mfma<<<dim3((Tn / 128) * Bn * Hn), dim3(512), 0, stream>>>(
        qkv, qkv + per, qkv + 2 * per, yb, zb);

    // output projection (M=8192, N=576) -> fp32: 576 blocks, XCD-swizzled
    gemm_mfma<1, 128><<<dim3((Mn / 128) * 9), dim3(256), 0, stream>>>(yb, wpb, nullptr, out);
}